// Round 4
// baseline (141.272 us; speedup 1.0000x reference)
//
#include <hip/hip_runtime.h>
#include <math.h>

// n=1024, raw=128, d=128, h=256
// prep (257 blocks):
//   blocks 0..255 (4 rows each): z = x@W_enc + b_enc (LDS);
//     a' = (z@W1[:d]) * log2e;  b' = (z@W1[d:] + b1) * log2e
//     ABi[n][1024]: [2k,2k+1] = {a'(k), exp2(a'(k))} for k<256 (A half)
//                   [512+2k, 512+2k+1] = {b'(k), exp2(b'(k))}   (B half)
//   block 256: base = b2 - SELU_AS * sum(W2)
// pair (32x32 grid, 256 thr, 4j x 1i per thread):
//   t' = a'[j,k] + b'[i,k]          (= log2e * t)
//   exp2(min(t',0)) == min(Ea*Eb, 1)  -> NO transcendentals in hot loop
//   acc1 += w*max(t',0); acc2 += w*min(Ea*Eb,1)
//   out = hsig( S_OVER_L2E*acc1 + SELU_AS*acc2 + base )

#define LOG2E       1.4426950408889634f
#define SELU_AS     1.7580993408473766f   // scale*alpha
#define S_OVER_L2E  0.7282921587620419f   // scale/log2e

typedef float v2f __attribute__((ext_vector_type(2)));

__global__ __launch_bounds__(256) void prep_kernel(
    const float* __restrict__ x, const float* __restrict__ W_enc,
    const float* __restrict__ b_enc, const float* __restrict__ W1,
    const float* __restrict__ b1, const float* __restrict__ W2,
    const float* __restrict__ b2, float* __restrict__ ABi,
    float* __restrict__ basep)
{
    __shared__ float zs[512];
    int t = threadIdx.x, b = blockIdx.x;
    if (b < 256) {
        int r0 = b << 2;
        int r = t >> 6;                   // wave-uniform row 0..3
        int dd = (t & 63) << 1;
        const float* xr = x + (size_t)(r0 + r) * 128;
        v2f z = { b_enc[dd], b_enc[dd + 1] };
#pragma unroll 8
        for (int dl = 0; dl < 128; ++dl) {
            float xv = xr[dl];
            v2f xx = { xv, xv };
            v2f wv = *(const v2f*)(W_enc + (size_t)dl * 128 + dd);
            z = __builtin_elementwise_fma(xx, wv, z);
        }
        zs[r * 128 + dd] = z.x;
        zs[r * 128 + dd + 1] = z.y;
        __syncthreads();

        int c = t;                        // h-column 0..255
        float b1c = b1[c];
        float accA0 = 0.f, accA1 = 0.f, accA2 = 0.f, accA3 = 0.f;
        float accB0 = b1c, accB1 = b1c, accB2 = b1c, accB3 = b1c;
        const float* w1a = W1 + c;
        const float* w1b = W1 + 128 * 256 + c;
#pragma unroll 4
        for (int dl = 0; dl < 128; ++dl) {
            float wa = w1a[(size_t)dl * 256];
            float wb = w1b[(size_t)dl * 256];
            float z0 = zs[dl], z1 = zs[128 + dl], z2 = zs[256 + dl], z3 = zs[384 + dl];
            accA0 = fmaf(z0, wa, accA0); accB0 = fmaf(z0, wb, accB0);
            accA1 = fmaf(z1, wa, accA1); accB1 = fmaf(z1, wb, accB1);
            accA2 = fmaf(z2, wa, accA2); accB2 = fmaf(z2, wb, accB2);
            accA3 = fmaf(z3, wa, accA3); accB3 = fmaf(z3, wb, accB3);
        }
        float aA[4] = {accA0, accA1, accA2, accA3};
        float aB[4] = {accB0, accB1, accB2, accB3};
#pragma unroll
        for (int r2 = 0; r2 < 4; ++r2) {
            float ap = aA[r2] * LOG2E;
            float bp = aB[r2] * LOG2E;
            float2 va = make_float2(ap, __builtin_amdgcn_exp2f(ap));
            float2 vb = make_float2(bp, __builtin_amdgcn_exp2f(bp));
            *(float2*)(ABi + (size_t)(r0 + r2) * 1024 + 2 * c) = va;
            *(float2*)(ABi + (size_t)(r0 + r2) * 1024 + 512 + 2 * c) = vb;
        }
    } else if (t < 64) {
        float s = W2[t] + W2[t + 64] + W2[t + 128] + W2[t + 192];
#pragma unroll
        for (int o = 32; o > 0; o >>= 1) s += __shfl_down(s, o);
        if (t == 0) basep[0] = fmaf(-SELU_AS, s, b2[0]);
    }
}

// 32x32 tile, 256 threads: thread -> j-quad tj=(t&7)*4, i row ti=t>>3.
// LDS: Aa[64][32], Ae[64][32] (planes, b128 reads), Bs[64][64] ({b,Eb}
// interleaved, b64 reads). XOR swizzle per k-row breaks staging conflicts.
__global__ __launch_bounds__(256, 4) void pair_kernel(
    const float* __restrict__ ABi, const float* __restrict__ W2,
    const float* __restrict__ basep, float* __restrict__ out)
{
    __shared__ __align__(16) float Aa[64 * 32];
    __shared__ __align__(16) float Ae[64 * 32];
    __shared__ __align__(16) float Bs[64 * 64];

    int t = threadIdx.x;
    int bj32 = blockIdx.x << 5, bi32 = blockIdx.y << 5;
    int tj = (t & 7) << 2;       // j-quad base 0..28
    int ti = t >> 3;             // i row 0..31
    int ti2 = ti << 1;

    int f = t & 31;              // k-pair group in staging
    int r8 = t >> 5;             // 0..7
    int kk0 = f << 1;            // 0..62
    int mA0 = (kk0 & 7) << 2, mA1 = ((kk0 + 1) & 7) << 2;
    int mB0 = (kk0 & 15) << 2, mB1 = ((kk0 + 1) & 15) << 2;

    v2f acc1a = {0.f, 0.f}, acc1b = {0.f, 0.f};
    v2f acc2a = {0.f, 0.f}, acc2b = {0.f, 0.f};
    const v2f vzero = {0.f, 0.f};
    const v2f vone  = {1.f, 1.f};

    for (int ch = 0; ch < 4; ++ch) {
        if (ch) __syncthreads();
        // stage A tile: 32 rows x 64 k (a, Ea) -> planes, transpose to [k][j]
#pragma unroll
        for (int p = 0; p < 4; ++p) {
            int j = r8 + (p << 3);
            float4 v = *(const float4*)(ABi + (size_t)(bj32 + j) * 1024 + (ch << 7) + (f << 2));
            Aa[(kk0 << 5) + (j ^ mA0)] = v.x;
            Ae[(kk0 << 5) + (j ^ mA0)] = v.y;
            Aa[((kk0 + 1) << 5) + (j ^ mA1)] = v.z;
            Ae[((kk0 + 1) << 5) + (j ^ mA1)] = v.w;
        }
        // stage B tile: 32 rows x 64 k {b, Eb} interleaved
#pragma unroll
        for (int p = 0; p < 4; ++p) {
            int i = r8 + (p << 3);
            float4 v = *(const float4*)(ABi + (size_t)(bi32 + i) * 1024 + 512 + (ch << 7) + (f << 2));
            *(float2*)&Bs[(kk0 << 6) + ((2 * i) ^ mB0)] = make_float2(v.x, v.y);
            *(float2*)&Bs[((kk0 + 1) << 6) + ((2 * i) ^ mB1)] = make_float2(v.z, v.w);
        }
        __syncthreads();

        const float* W2c = W2 + (ch << 6);
#pragma unroll 8
        for (int k = 0; k < 64; ++k) {
            float w = W2c[k];                       // uniform -> s_load
            int mA = (k & 7) << 2;
            int mB = (k & 15) << 2;
            float4 av4 = *(const float4*)&Aa[(k << 5) + (tj ^ mA)];
            float4 ev4 = *(const float4*)&Ae[(k << 5) + (tj ^ mA)];
            float2 bv  = *(const float2*)&Bs[(k << 6) + (ti2 ^ mB)];
            v2f a01 = { av4.x, av4.y }, a23 = { av4.z, av4.w };
            v2f e01 = { ev4.x, ev4.y }, e23 = { ev4.z, ev4.w };
            v2f bb = { bv.x, bv.x };
            v2f eb = { bv.y, bv.y };
            v2f wv = { w, w };
            v2f t01 = a01 + bb, t23 = a23 + bb;
            v2f p01 = e01 * eb, p23 = e23 * eb;
            t01 = __builtin_elementwise_max(t01, vzero);
            t23 = __builtin_elementwise_max(t23, vzero);
            p01 = __builtin_elementwise_min(p01, vone);
            p23 = __builtin_elementwise_min(p23, vone);
            acc1a = __builtin_elementwise_fma(wv, t01, acc1a);
            acc1b = __builtin_elementwise_fma(wv, t23, acc1b);
            acc2a = __builtin_elementwise_fma(wv, p01, acc2a);
            acc2b = __builtin_elementwise_fma(wv, p23, acc2b);
        }
    }

    float base = basep[0];
    v2f basev = { base, base };
    v2f c1 = { S_OVER_L2E, S_OVER_L2E };
    v2f c2 = { SELU_AS, SELU_AS };
    v2f v01 = __builtin_elementwise_fma(c1, acc1a, __builtin_elementwise_fma(c2, acc2a, basev));
    v2f v23 = __builtin_elementwise_fma(c1, acc1b, __builtin_elementwise_fma(c2, acc2b, basev));
    float4 o;
    o.x = __saturatef(v01.x * (1.0f / 6.0f) + 0.5f);
    o.y = __saturatef(v01.y * (1.0f / 6.0f) + 0.5f);
    o.z = __saturatef(v23.x * (1.0f / 6.0f) + 0.5f);
    o.w = __saturatef(v23.y * (1.0f / 6.0f) + 0.5f);
    *(float4*)(out + (size_t)(bi32 + ti) * 1024 + bj32 + tj) = o;
}

extern "C" void kernel_launch(void* const* d_in, const int* in_sizes, int n_in,
                              void* d_out, int out_size, void* d_ws, size_t ws_size,
                              hipStream_t stream) {
    const float* x     = (const float*)d_in[0];
    const float* W_enc = (const float*)d_in[1];
    const float* b_enc = (const float*)d_in[2];
    const float* W1    = (const float*)d_in[3];
    const float* b1    = (const float*)d_in[4];
    const float* W2    = (const float*)d_in[5];
    const float* b2    = (const float*)d_in[6];
    float* out = (float*)d_out;

    float* ws   = (float*)d_ws;
    float* ABi  = ws;               // 1024*1024 floats = 4 MB
    float* basep = ws + 1024 * 1024;

    prep_kernel<<<257, 256, 0, stream>>>(x, W_enc, b_enc, W1, b1, W2, b2, ABi, basep);
    pair_kernel<<<dim3(32, 32), 256, 0, stream>>>(ABi, W2, basep, out);
}

// Round 5
// 127.727 us; speedup vs baseline: 1.1060x; 1.1060x over previous
//
#include <hip/hip_runtime.h>
#include <math.h>

// n=1024, raw=128, d=128, h=256
// prep (257 blocks): blocks 0..255 (4 n-rows each): z = x@W_enc + b_enc (LDS);
//   a' = (z@W1[:d])*log2e; b' = (z@W1[d:]+b1)*log2e
//   writes TRANSPOSED planes: PAa[k][n]=a', PAe[k][n]=exp2(a'),
//                             PBb[k][n]=b', PBe[k][n]=exp2(b')
//   block 256: base = b2 - SELU_AS*sum(W2)
// pair (grid 16x32, 256 thr, 4j x 2i per thread, tile 64j x 32i):
//   t' = a'+b'; exp2(min(t',0)) == min(Ea*Eb, 1)  -> no transcendentals
//   acc1 += w*max(t',0); acc2 += w*min(Ea*Eb,1)
//   out = hsig( S_OVER_L2E*acc1 + SELU_AS*acc2 + base )

#define LOG2E       1.4426950408889634f
#define SELU_AS     1.7580993408473766f   // scale*alpha
#define S_OVER_L2E  0.7282921587620419f   // scale/log2e

typedef float v2f __attribute__((ext_vector_type(2)));

__global__ __launch_bounds__(256) void prep_kernel(
    const float* __restrict__ x, const float* __restrict__ W_enc,
    const float* __restrict__ b_enc, const float* __restrict__ W1,
    const float* __restrict__ b1, const float* __restrict__ W2,
    const float* __restrict__ b2, float* __restrict__ PAa,
    float* __restrict__ PAe, float* __restrict__ PBb,
    float* __restrict__ PBe, float* __restrict__ basep)
{
    __shared__ float zs[512];
    int t = threadIdx.x, b = blockIdx.x;
    if (b < 256) {
        int r0 = b << 2;
        int r = t >> 6;                   // wave-uniform row 0..3
        int dd = (t & 63) << 1;
        const float* xr = x + (size_t)(r0 + r) * 128;
        v2f z = { b_enc[dd], b_enc[dd + 1] };
#pragma unroll 8
        for (int dl = 0; dl < 128; ++dl) {
            float xv = xr[dl];
            v2f xx = { xv, xv };
            v2f wv = *(const v2f*)(W_enc + (size_t)dl * 128 + dd);
            z = __builtin_elementwise_fma(xx, wv, z);
        }
        zs[r * 128 + dd] = z.x;
        zs[r * 128 + dd + 1] = z.y;
        __syncthreads();

        int c = t;                        // h-column (= k) 0..255
        float b1c = b1[c];
        float accA0 = 0.f, accA1 = 0.f, accA2 = 0.f, accA3 = 0.f;
        float accB0 = b1c, accB1 = b1c, accB2 = b1c, accB3 = b1c;
        const float* w1a = W1 + c;
        const float* w1b = W1 + 128 * 256 + c;
#pragma unroll 4
        for (int dl = 0; dl < 128; ++dl) {
            float wa = w1a[(size_t)dl * 256];
            float wb = w1b[(size_t)dl * 256];
            float z0 = zs[dl], z1 = zs[128 + dl], z2 = zs[256 + dl], z3 = zs[384 + dl];
            accA0 = fmaf(z0, wa, accA0); accB0 = fmaf(z0, wb, accB0);
            accA1 = fmaf(z1, wa, accA1); accB1 = fmaf(z1, wb, accB1);
            accA2 = fmaf(z2, wa, accA2); accB2 = fmaf(z2, wb, accB2);
            accA3 = fmaf(z3, wa, accA3); accB3 = fmaf(z3, wb, accB3);
        }
        float4 va, ve, wb_, we_;
        va.x = accA0 * LOG2E; va.y = accA1 * LOG2E;
        va.z = accA2 * LOG2E; va.w = accA3 * LOG2E;
        wb_.x = accB0 * LOG2E; wb_.y = accB1 * LOG2E;
        wb_.z = accB2 * LOG2E; wb_.w = accB3 * LOG2E;
        ve.x = __builtin_amdgcn_exp2f(va.x); ve.y = __builtin_amdgcn_exp2f(va.y);
        ve.z = __builtin_amdgcn_exp2f(va.z); ve.w = __builtin_amdgcn_exp2f(va.w);
        we_.x = __builtin_amdgcn_exp2f(wb_.x); we_.y = __builtin_amdgcn_exp2f(wb_.y);
        we_.z = __builtin_amdgcn_exp2f(wb_.z); we_.w = __builtin_amdgcn_exp2f(wb_.w);
        size_t o = (size_t)c * 1024 + r0;           // transposed: [k][n]
        *(float4*)(PAa + o) = va;
        *(float4*)(PAe + o) = ve;
        *(float4*)(PBb + o) = wb_;
        *(float4*)(PBe + o) = we_;
    } else if (t < 64) {
        float s = W2[t] + W2[t + 64] + W2[t + 128] + W2[t + 192];
#pragma unroll
        for (int o = 32; o > 0; o >>= 1) s += __shfl_down(s, o);
        if (t == 0) basep[0] = fmaf(-SELU_AS, s, b2[0]);
    }
}

// Tile 64j x 32i per block, 256 threads, 4j x 2i per thread.
// LDS: Asm[64 k][a*64 | Ea*64], Bsm[64 k][b*32 | Eb*32]. All staging writes
// and compute reads hit the even bank-distribution floor (no conflicts).
__global__ __launch_bounds__(256, 2) void pair_kernel(
    const float* __restrict__ PAa, const float* __restrict__ PAe,
    const float* __restrict__ PBb, const float* __restrict__ PBe,
    const float* __restrict__ W2, const float* __restrict__ basep,
    float* __restrict__ out)
{
    __shared__ __align__(16) float Asm[64 * 128];   // 32 KB
    __shared__ __align__(16) float Bsm[64 * 64];    // 16 KB

    int t = threadIdx.x;
    int bj64 = blockIdx.x << 6;
    int bi32 = blockIdx.y << 5;
    int tj4 = (t & 15) << 2;
    int ti2 = (t >> 4) << 1;

    v2f accm[2][2] = {{{0.f,0.f},{0.f,0.f}},{{0.f,0.f},{0.f,0.f}}};  // [i][jp]
    v2f acce[2][2] = {{{0.f,0.f},{0.f,0.f}},{{0.f,0.f},{0.f,0.f}}};
    const v2f vzero = {0.f, 0.f};
    const v2f vone  = {1.f, 1.f};

    // staging maps (precompute)
    int a_col = (t & 15) << 2;          // 0..60
    int a_half = (t >> 4) & 1;
    int a_k = t >> 5;                   // 0..7 (+2p... actually p*2 + t>>5)
    int b_col = (t & 7) << 2;           // 0..28
    int b_half = (t >> 3) & 1;
    int b_k = t >> 4;                   // 0..15 (+p*16)

    for (int kc = 0; kc < 4; ++kc) {
        int k0 = kc << 6;
        if (kc) __syncthreads();
        // stage A chunk: 64 k-rows x 128 floats (a|Ea), 8 b128/thread
#pragma unroll
        for (int p = 0; p < 8; ++p) {
            int f4 = (p << 10) + (t << 2);          // 0..8188
            int k_l = f4 >> 7;
            const float* src = (a_half ? PAe : PAa)
                + (size_t)(k0 + k_l) * 1024 + bj64 + a_col;
            *(float4*)&Asm[f4] = *(const float4*)src;
        }
        // stage B chunk: 64 k-rows x 64 floats (b|Eb), 4 b128/thread
#pragma unroll
        for (int p = 0; p < 4; ++p) {
            int f4 = (p << 10) + (t << 2);          // 0..4092
            int k_l = f4 >> 6;
            const float* src = (b_half ? PBe : PBb)
                + (size_t)(k0 + k_l) * 1024 + bi32 + b_col;
            *(float4*)&Bsm[f4] = *(const float4*)src;
        }
        __syncthreads();

        const float* W2c = W2 + k0;
#pragma unroll 4
        for (int k = 0; k < 64; ++k) {
            float w = W2c[k];                        // uniform -> s_load
            float4 a4 = *(const float4*)&Asm[(k << 7) + tj4];
            float4 e4 = *(const float4*)&Asm[(k << 7) + 64 + tj4];
            float2 bb2 = *(const float2*)&Bsm[(k << 6) + ti2];
            float2 eb2 = *(const float2*)&Bsm[(k << 6) + 32 + ti2];
            v2f a01 = { a4.x, a4.y }, a23 = { a4.z, a4.w };
            v2f e01 = { e4.x, e4.y }, e23 = { e4.z, e4.w };
            v2f wv = { w, w };
#pragma unroll
            for (int i = 0; i < 2; ++i) {
                float bi = i ? bb2.y : bb2.x;
                float ei = i ? eb2.y : eb2.x;
                v2f bb = { bi, bi };
                v2f ee = { ei, ei };
                v2f t01 = a01 + bb, t23 = a23 + bb;
                v2f p01 = e01 * ee, p23 = e23 * ee;
                t01 = __builtin_elementwise_max(t01, vzero);
                t23 = __builtin_elementwise_max(t23, vzero);
                p01 = __builtin_elementwise_min(p01, vone);
                p23 = __builtin_elementwise_min(p23, vone);
                accm[i][0] = __builtin_elementwise_fma(wv, t01, accm[i][0]);
                accm[i][1] = __builtin_elementwise_fma(wv, t23, accm[i][1]);
                acce[i][0] = __builtin_elementwise_fma(wv, p01, acce[i][0]);
                acce[i][1] = __builtin_elementwise_fma(wv, p23, acce[i][1]);
            }
        }
    }

    float base = basep[0];
    v2f basev = { base, base };
    v2f c1 = { S_OVER_L2E, S_OVER_L2E };
    v2f c2 = { SELU_AS, SELU_AS };
#pragma unroll
    for (int i = 0; i < 2; ++i) {
        v2f v01 = __builtin_elementwise_fma(c1, accm[i][0],
                  __builtin_elementwise_fma(c2, acce[i][0], basev));
        v2f v23 = __builtin_elementwise_fma(c1, accm[i][1],
                  __builtin_elementwise_fma(c2, acce[i][1], basev));
        float4 o;
        o.x = __saturatef(v01.x * (1.0f / 6.0f) + 0.5f);
        o.y = __saturatef(v01.y * (1.0f / 6.0f) + 0.5f);
        o.z = __saturatef(v23.x * (1.0f / 6.0f) + 0.5f);
        o.w = __saturatef(v23.y * (1.0f / 6.0f) + 0.5f);
        *(float4*)(out + (size_t)(bi32 + ti2 + i) * 1024 + bj64 + tj4) = o;
    }
}

extern "C" void kernel_launch(void* const* d_in, const int* in_sizes, int n_in,
                              void* d_out, int out_size, void* d_ws, size_t ws_size,
                              hipStream_t stream) {
    const float* x     = (const float*)d_in[0];
    const float* W_enc = (const float*)d_in[1];
    const float* b_enc = (const float*)d_in[2];
    const float* W1    = (const float*)d_in[3];
    const float* b1    = (const float*)d_in[4];
    const float* W2    = (const float*)d_in[5];
    const float* b2    = (const float*)d_in[6];
    float* out = (float*)d_out;

    float* ws = (float*)d_ws;
    const int PLANE = 256 * 1024;
    float* PAa = ws;
    float* PAe = ws + PLANE;
    float* PBb = ws + 2 * PLANE;
    float* PBe = ws + 3 * PLANE;
    float* basep = ws + 4 * PLANE;

    prep_kernel<<<257, 256, 0, stream>>>(x, W_enc, b_enc, W1, b1, W2, b2,
                                         PAa, PAe, PBb, PBe, basep);
    pair_kernel<<<dim3(16, 32), 256, 0, stream>>>(PAa, PAe, PBb, PBe, W2,
                                                  basep, out);
}

// Round 6
// 127.701 us; speedup vs baseline: 1.1063x; 1.0002x over previous
//
#include <hip/hip_runtime.h>
#include <math.h>

// n=1024, raw=128, d=128, h=256
// prep (257 blocks): blocks 0..255 (4 n-rows each): z = x@W_enc + b_enc (LDS);
//   a' = (z@W1[:d])*log2e; b' = (z@W1[d:]+b1)*log2e
//   Output planes, k-major, pair-interleaved:
//     PAI[k][4*m .. 4*m+3] = { a'(2m), a'(2m+1), exp2(a'(2m)), exp2(a'(2m+1)) }
//     PBI likewise for b'.                      (row = 2048 floats)
//   block 256: base = b2 - SELU_AS*sum(W2)
// pair (grid 32x32, 256 thr, tile 32j x 32i, 2j x 2i per thread):
//   t' = a'+b';  exp2(min(t',0)) == min(Ea*Eb, 1)   -> no transcendentals
//   acc1 += w*max(t',0); acc2 += w*min(Ea*Eb,1)
//   out = hsig( S_OVER_L2E*acc1 + SELU_AS*acc2 + base )

#define LOG2E       1.4426950408889634f
#define SELU_AS     1.7580993408473766f   // scale*alpha
#define S_OVER_L2E  0.7282921587620419f   // scale/log2e

typedef float v2f __attribute__((ext_vector_type(2)));

__global__ __launch_bounds__(256) void prep_kernel(
    const float* __restrict__ x, const float* __restrict__ W_enc,
    const float* __restrict__ b_enc, const float* __restrict__ W1,
    const float* __restrict__ b1, const float* __restrict__ W2,
    const float* __restrict__ b2, float* __restrict__ PAI,
    float* __restrict__ PBI, float* __restrict__ basep)
{
    __shared__ float zs[512];
    int t = threadIdx.x, b = blockIdx.x;
    if (b < 256) {
        int r0 = b << 2;
        int r = t >> 6;                   // wave-uniform row 0..3
        int dd = (t & 63) << 1;
        const float* xr = x + (size_t)(r0 + r) * 128;
        v2f z = { b_enc[dd], b_enc[dd + 1] };
#pragma unroll 8
        for (int dl = 0; dl < 128; ++dl) {
            float xv = xr[dl];
            v2f xx = { xv, xv };
            v2f wv = *(const v2f*)(W_enc + (size_t)dl * 128 + dd);
            z = __builtin_elementwise_fma(xx, wv, z);
        }
        zs[r * 128 + dd] = z.x;
        zs[r * 128 + dd + 1] = z.y;
        __syncthreads();

        int c = t;                        // h-column (= k) 0..255
        float b1c = b1[c];
        float accA0 = 0.f, accA1 = 0.f, accA2 = 0.f, accA3 = 0.f;
        float accB0 = b1c, accB1 = b1c, accB2 = b1c, accB3 = b1c;
        const float* w1a = W1 + c;
        const float* w1b = W1 + 128 * 256 + c;
#pragma unroll 4
        for (int dl = 0; dl < 128; ++dl) {
            float wa = w1a[(size_t)dl * 256];
            float wb = w1b[(size_t)dl * 256];
            float z0 = zs[dl], z1 = zs[128 + dl], z2 = zs[256 + dl], z3 = zs[384 + dl];
            accA0 = fmaf(z0, wa, accA0); accB0 = fmaf(z0, wb, accB0);
            accA1 = fmaf(z1, wa, accA1); accB1 = fmaf(z1, wb, accB1);
            accA2 = fmaf(z2, wa, accA2); accB2 = fmaf(z2, wb, accB2);
            accA3 = fmaf(z3, wa, accA3); accB3 = fmaf(z3, wb, accB3);
        }
        float a0 = accA0 * LOG2E, a1 = accA1 * LOG2E;
        float a2 = accA2 * LOG2E, a3 = accA3 * LOG2E;
        float bb0 = accB0 * LOG2E, bb1 = accB1 * LOG2E;
        float bb2v = accB2 * LOG2E, bb3 = accB3 * LOG2E;
        float4 pa0, pa1, pb0, pb1;
        pa0.x = a0; pa0.y = a1;
        pa0.z = __builtin_amdgcn_exp2f(a0); pa0.w = __builtin_amdgcn_exp2f(a1);
        pa1.x = a2; pa1.y = a3;
        pa1.z = __builtin_amdgcn_exp2f(a2); pa1.w = __builtin_amdgcn_exp2f(a3);
        pb0.x = bb0; pb0.y = bb1;
        pb0.z = __builtin_amdgcn_exp2f(bb0); pb0.w = __builtin_amdgcn_exp2f(bb1);
        pb1.x = bb2v; pb1.y = bb3;
        pb1.z = __builtin_amdgcn_exp2f(bb2v); pb1.w = __builtin_amdgcn_exp2f(bb3);
        size_t o = (size_t)c * 2048 + (size_t)(r0 << 1);  // [k][4*(n/2)]
        *(float4*)(PAI + o) = pa0;
        *(float4*)(PAI + o + 4) = pa1;
        *(float4*)(PBI + o) = pb0;
        *(float4*)(PBI + o + 4) = pb1;
    } else if (t < 64) {
        float s = W2[t] + W2[t + 64] + W2[t + 128] + W2[t + 192];
#pragma unroll
        for (int o = 32; o > 0; o >>= 1) s += __shfl_down(s, o);
        if (t == 0) basep[0] = fmaf(-SELU_AS, s, b2[0]);
    }
}

// Tile 32j x 32i, 256 threads, 2j x 2i per thread, grid (32,32) = 1024 blocks
// -> 4 blocks/CU (LDS 32 KB), 16 waves/CU. Compute reads: 1 ds_read_b128 per
// matrix per k, pk-register-aligned {a0,a1,e0,e1}; staging fully contiguous.
__global__ __launch_bounds__(256, 4) void pair_kernel(
    const float* __restrict__ PAI, const float* __restrict__ PBI,
    const float* __restrict__ W2, const float* __restrict__ basep,
    float* __restrict__ out)
{
    __shared__ __align__(16) float As[64 * 64];   // 16 KB: [k][{a,a,e,e} x16]
    __shared__ __align__(16) float Bs[64 * 64];   // 16 KB

    int t = threadIdx.x;
    int bj32 = blockIdx.x << 5, bi32 = blockIdx.y << 5;
    int jp = t & 15;             // j-pair 0..15
    int ip = t >> 4;             // i-pair 0..15

    v2f acc1[2] = {{0.f, 0.f}, {0.f, 0.f}};   // [i] x {j0,j1}
    v2f acc2[2] = {{0.f, 0.f}, {0.f, 0.f}};
    const v2f vzero = {0.f, 0.f};
    const v2f vone  = {1.f, 1.f};

    for (int kc = 0; kc < 4; ++kc) {
        int k0 = kc << 6;
        if (kc) __syncthreads();
#pragma unroll
        for (int p = 0; p < 4; ++p) {
            int f = (p << 8) + t;            // float4 index 0..1023
            int k_l = f >> 4;
            int col = (f & 15) << 2;
            size_t go = (size_t)(k0 + k_l) * 2048;
            *(float4*)&As[f << 2] = *(const float4*)(PAI + go + (bj32 << 1) + col);
            *(float4*)&Bs[f << 2] = *(const float4*)(PBI + go + (bi32 << 1) + col);
        }
        __syncthreads();

        const float* W2c = W2 + k0;
#pragma unroll 8
        for (int k = 0; k < 64; ++k) {
            float w = W2c[k];                            // uniform -> s_load
            float4 av = *(const float4*)&As[(k << 6) + (jp << 2)];
            float4 bv = *(const float4*)&Bs[(k << 6) + (ip << 2)];
            v2f a01 = { av.x, av.y }, e01 = { av.z, av.w };
            v2f wv = { w, w };
#pragma unroll
            for (int i = 0; i < 2; ++i) {
                float bi = i ? bv.y : bv.x;
                float ei = i ? bv.w : bv.z;
                v2f bbv = { bi, bi };
                v2f eev = { ei, ei };
                v2f t01 = a01 + bbv;
                v2f p01 = e01 * eev;
                t01 = __builtin_elementwise_max(t01, vzero);
                p01 = __builtin_elementwise_min(p01, vone);
                acc1[i] = __builtin_elementwise_fma(wv, t01, acc1[i]);
                acc2[i] = __builtin_elementwise_fma(wv, p01, acc2[i]);
            }
        }
    }

    float base = basep[0];
    v2f basev = { base, base };
    v2f c1 = { S_OVER_L2E, S_OVER_L2E };
    v2f c2 = { SELU_AS, SELU_AS };
#pragma unroll
    for (int i = 0; i < 2; ++i) {
        v2f v = __builtin_elementwise_fma(c1, acc1[i],
                __builtin_elementwise_fma(c2, acc2[i], basev));
        float2 o;
        o.x = __saturatef(v.x * (1.0f / 6.0f) + 0.5f);
        o.y = __saturatef(v.y * (1.0f / 6.0f) + 0.5f);
        *(float2*)(out + (size_t)(bi32 + (ip << 1) + i) * 1024
                       + bj32 + (jp << 1)) = o;
    }
}

extern "C" void kernel_launch(void* const* d_in, const int* in_sizes, int n_in,
                              void* d_out, int out_size, void* d_ws, size_t ws_size,
                              hipStream_t stream) {
    const float* x     = (const float*)d_in[0];
    const float* W_enc = (const float*)d_in[1];
    const float* b_enc = (const float*)d_in[2];
    const float* W1    = (const float*)d_in[3];
    const float* b1    = (const float*)d_in[4];
    const float* W2    = (const float*)d_in[5];
    const float* b2    = (const float*)d_in[6];
    float* out = (float*)d_out;

    float* ws = (float*)d_ws;
    const int PLANE = 256 * 2048;          // 2 MB each
    float* PAI = ws;
    float* PBI = ws + PLANE;
    float* basep = ws + 2 * PLANE;

    prep_kernel<<<257, 256, 0, stream>>>(x, W_enc, b_enc, W1, b1, W2, b2,
                                         PAI, PBI, basep);
    pair_kernel<<<dim3(32, 32), 256, 0, stream>>>(PAI, PBI, W2, basep, out);
}

// Round 7
// 116.536 us; speedup vs baseline: 1.2123x; 1.0958x over previous
//
#include <hip/hip_runtime.h>
#include <math.h>

// n=1024, raw=128, d=128, h=256
// prep (257 blocks): blocks 0..255 (4 n-rows, 1 h-col per thread):
//   z = x@W_enc + b_enc (LDS); a' = (z@W1[:d])*log2e; b' = (z@W1[d:]+b1)*log2e
//   e = exp2(a'), f = exp2(b'). Packed into f16 half2 pairs along k
//   (shfl_xor(1) exchange): planes [k2][n] of u32:
//     PAa[k2][n] = half2{a'(n,2k2), a'(n,2k2+1)}   PAe = half2{e,e}
//     PBb, PBe likewise for b half. Even lanes write A planes, odd B planes.
//   block 256: base = b2 - SELU_AS*sum(W2); W2h[k2] = half2{w(2k2),w(2k2+1)}
// pair (grid 16x16, 256 thr, tile 64x64, 4j x 4i per thread):
//   t2 = a'+b' (pk_add_f16); p2 = e*f (pk_mul); m2 = max(t2,0); n2 = min(p2,1)
//   acc1 = fdot2(m2, w2, acc1); acc2 = fdot2(n2, w2, acc2)   // 2 k-steps/instr
//   out = hsig( S_OVER_L2E*acc1 + SELU_AS*acc2 + base )
//   exp2(min(t,0)) == min(Ea*Eb,1) -> no transcendentals, no branches.

#define LOG2E       1.4426950408889634f
#define SELU_AS     1.7580993408473766f   // scale*alpha
#define S_OVER_L2E  0.7282921587620419f   // scale/log2e

typedef float v2f __attribute__((ext_vector_type(2)));
typedef _Float16 v2h __attribute__((ext_vector_type(2)));
typedef unsigned int u32;

__global__ __launch_bounds__(256) void prep_kernel(
    const float* __restrict__ x, const float* __restrict__ W_enc,
    const float* __restrict__ b_enc, const float* __restrict__ W1,
    const float* __restrict__ b1, const float* __restrict__ W2,
    const float* __restrict__ b2, u32* __restrict__ PAa,
    u32* __restrict__ PAe, u32* __restrict__ PBb, u32* __restrict__ PBe,
    u32* __restrict__ W2h, float* __restrict__ basep)
{
    __shared__ float zs[512];
    int t = threadIdx.x, b = blockIdx.x;
    if (b < 256) {
        int r0 = b << 2;
        int r = t >> 6;                   // wave-uniform row 0..3
        int dd = (t & 63) << 1;
        const float* xr = x + (size_t)(r0 + r) * 128;
        v2f z = { b_enc[dd], b_enc[dd + 1] };
#pragma unroll 8
        for (int dl = 0; dl < 128; ++dl) {
            float xv = xr[dl];
            v2f xx = { xv, xv };
            v2f wv = *(const v2f*)(W_enc + (size_t)dl * 128 + dd);
            z = __builtin_elementwise_fma(xx, wv, z);
        }
        zs[r * 128 + dd] = z.x;
        zs[r * 128 + dd + 1] = z.y;
        __syncthreads();

        int c = t;                        // h-column (= k) 0..255
        float b1c = b1[c];
        float accA0 = 0.f, accA1 = 0.f, accA2 = 0.f, accA3 = 0.f;
        float accB0 = b1c, accB1 = b1c, accB2 = b1c, accB3 = b1c;
        const float* w1a = W1 + c;
        const float* w1b = W1 + 128 * 256 + c;
#pragma unroll 4
        for (int dl = 0; dl < 128; ++dl) {
            float wa = w1a[(size_t)dl * 256];
            float wb = w1b[(size_t)dl * 256];
            float z0 = zs[dl], z1 = zs[128 + dl], z2 = zs[256 + dl], z3 = zs[384 + dl];
            accA0 = fmaf(z0, wa, accA0); accB0 = fmaf(z0, wb, accB0);
            accA1 = fmaf(z1, wa, accA1); accB1 = fmaf(z1, wb, accB1);
            accA2 = fmaf(z2, wa, accA2); accB2 = fmaf(z2, wb, accB2);
            accA3 = fmaf(z3, wa, accA3); accB3 = fmaf(z3, wb, accB3);
        }
        float ar[4] = { accA0 * LOG2E, accA1 * LOG2E, accA2 * LOG2E, accA3 * LOG2E };
        float br[4] = { accB0 * LOG2E, accB1 * LOG2E, accB2 * LOG2E, accB3 * LOG2E };
        u32 pa[4], pe[4], pb[4], pf[4];
        bool odd = (c & 1);
#pragma unroll
        for (int r2 = 0; r2 < 4; ++r2) {
            float er = __builtin_amdgcn_exp2f(ar[r2]);
            float fr = __builtin_amdgcn_exp2f(br[r2]);
            float aN = __shfl_xor(ar[r2], 1);
            float eN = __shfl_xor(er, 1);
            float bN = __shfl_xor(br[r2], 1);
            float fN = __shfl_xor(fr, 1);
            // even lane: {own, neighbor}; odd lane: {neighbor, own}
            pa[r2] = __builtin_bit_cast(u32, __builtin_amdgcn_cvt_pkrtz(ar[r2], aN));
            pe[r2] = __builtin_bit_cast(u32, __builtin_amdgcn_cvt_pkrtz(er, eN));
            pb[r2] = __builtin_bit_cast(u32, __builtin_amdgcn_cvt_pkrtz(bN, br[r2]));
            pf[r2] = __builtin_bit_cast(u32, __builtin_amdgcn_cvt_pkrtz(fN, fr));
        }
        size_t o = (size_t)(c >> 1) * 1024 + r0;    // [k2][n]
        if (!odd) {
            *(uint4*)(PAa + o) = make_uint4(pa[0], pa[1], pa[2], pa[3]);
            *(uint4*)(PAe + o) = make_uint4(pe[0], pe[1], pe[2], pe[3]);
        } else {
            *(uint4*)(PBb + o) = make_uint4(pb[0], pb[1], pb[2], pb[3]);
            *(uint4*)(PBe + o) = make_uint4(pf[0], pf[1], pf[2], pf[3]);
        }
    } else {
        if (t < 128) {
            W2h[t] = __builtin_bit_cast(u32,
                __builtin_amdgcn_cvt_pkrtz(W2[2 * t], W2[2 * t + 1]));
        }
        if (t < 64) {
            float s = W2[t] + W2[t + 64] + W2[t + 128] + W2[t + 192];
#pragma unroll
            for (int o = 32; o > 0; o >>= 1) s += __shfl_down(s, o);
            if (t == 0) basep[0] = fmaf(-SELU_AS, s, b2[0]);
        }
    }
}

// Tile 64j x 64i, 256 thr, 4j x 4i per thread, grid (16,16) = 256 blocks.
// LDS 64 KB: Aa/Ae/Bb/Be [64 k2][64 n] u32 (one 64-k2 chunk = 128 k, 2 chunks).
// Per thread per k2 (2 k-steps): 4 ds_read_b128 -> 32 elem-k; 96 VALU instr.
__global__ __launch_bounds__(256) void pair_kernel(
    const u32* __restrict__ PAa, const u32* __restrict__ PAe,
    const u32* __restrict__ PBb, const u32* __restrict__ PBe,
    const u32* __restrict__ W2h, const float* __restrict__ basep,
    float* __restrict__ out)
{
    __shared__ __align__(16) u32 Aa[64 * 64];
    __shared__ __align__(16) u32 Ae[64 * 64];
    __shared__ __align__(16) u32 Bb[64 * 64];
    __shared__ __align__(16) u32 Be[64 * 64];

    int t = threadIdx.x;
    int bj64 = blockIdx.x << 6, bi64 = blockIdx.y << 6;
    int tjx = t & 15, tiy = t >> 4;
    int tj4 = tjx << 2, ti4 = tiy << 2;

    float acc1[4][4], acc2[4][4];
#pragma unroll
    for (int i = 0; i < 4; ++i)
#pragma unroll
        for (int j = 0; j < 4; ++j) { acc1[i][j] = 0.f; acc2[i][j] = 0.f; }

    const v2h hzero = { (_Float16)0.f, (_Float16)0.f };
    const v2h hone  = { (_Float16)1.f, (_Float16)1.f };

    for (int ch = 0; ch < 2; ++ch) {
        if (ch) __syncthreads();
#pragma unroll
        for (int p = 0; p < 4; ++p) {
            int q = (p << 8) + t;            // uint4 quad idx 0..1023
            int k2l = q >> 4;
            int jq = (q & 15) << 2;
            size_t go = (size_t)((ch << 6) + k2l) * 1024;
            *(uint4*)&Aa[q << 2] = *(const uint4*)(PAa + go + bj64 + jq);
            *(uint4*)&Ae[q << 2] = *(const uint4*)(PAe + go + bj64 + jq);
            *(uint4*)&Bb[q << 2] = *(const uint4*)(PBb + go + bi64 + jq);
            *(uint4*)&Be[q << 2] = *(const uint4*)(PBe + go + bi64 + jq);
        }
        __syncthreads();

        const u32* W2c = W2h + (ch << 6);
#pragma unroll 4
        for (int k2 = 0; k2 < 64; ++k2) {
            v2h w2 = __builtin_bit_cast(v2h, W2c[k2]);       // uniform
            uint4 qa = *(const uint4*)&Aa[(k2 << 6) + tj4];
            uint4 qe = *(const uint4*)&Ae[(k2 << 6) + tj4];
            uint4 qb = *(const uint4*)&Bb[(k2 << 6) + ti4];
            uint4 qf = *(const uint4*)&Be[(k2 << 6) + ti4];
            v2h a[4] = { __builtin_bit_cast(v2h, qa.x), __builtin_bit_cast(v2h, qa.y),
                         __builtin_bit_cast(v2h, qa.z), __builtin_bit_cast(v2h, qa.w) };
            v2h e[4] = { __builtin_bit_cast(v2h, qe.x), __builtin_bit_cast(v2h, qe.y),
                         __builtin_bit_cast(v2h, qe.z), __builtin_bit_cast(v2h, qe.w) };
            v2h bb[4] = { __builtin_bit_cast(v2h, qb.x), __builtin_bit_cast(v2h, qb.y),
                          __builtin_bit_cast(v2h, qb.z), __builtin_bit_cast(v2h, qb.w) };
            v2h ff[4] = { __builtin_bit_cast(v2h, qf.x), __builtin_bit_cast(v2h, qf.y),
                          __builtin_bit_cast(v2h, qf.z), __builtin_bit_cast(v2h, qf.w) };
#pragma unroll
            for (int i = 0; i < 4; ++i) {
#pragma unroll
                for (int j = 0; j < 4; ++j) {
                    v2h t2 = a[j] + bb[i];                   // v_pk_add_f16
                    v2h p2 = e[j] * ff[i];                   // v_pk_mul_f16
                    v2h m2 = __builtin_elementwise_max(t2, hzero);
                    v2h n2 = __builtin_elementwise_min(p2, hone);
                    acc1[i][j] = __builtin_amdgcn_fdot2(m2, w2, acc1[i][j], false);
                    acc2[i][j] = __builtin_amdgcn_fdot2(n2, w2, acc2[i][j], false);
                }
            }
        }
    }

    float base = basep[0];
#pragma unroll
    for (int i = 0; i < 4; ++i) {
        float4 o;
        float v0 = fmaf(S_OVER_L2E, acc1[i][0], fmaf(SELU_AS, acc2[i][0], base));
        float v1 = fmaf(S_OVER_L2E, acc1[i][1], fmaf(SELU_AS, acc2[i][1], base));
        float v2 = fmaf(S_OVER_L2E, acc1[i][2], fmaf(SELU_AS, acc2[i][2], base));
        float v3 = fmaf(S_OVER_L2E, acc1[i][3], fmaf(SELU_AS, acc2[i][3], base));
        o.x = __saturatef(v0 * (1.0f / 6.0f) + 0.5f);
        o.y = __saturatef(v1 * (1.0f / 6.0f) + 0.5f);
        o.z = __saturatef(v2 * (1.0f / 6.0f) + 0.5f);
        o.w = __saturatef(v3 * (1.0f / 6.0f) + 0.5f);
        *(float4*)(out + (size_t)(bi64 + ti4 + i) * 1024 + bj64 + tj4) = o;
    }
}

extern "C" void kernel_launch(void* const* d_in, const int* in_sizes, int n_in,
                              void* d_out, int out_size, void* d_ws, size_t ws_size,
                              hipStream_t stream) {
    const float* x     = (const float*)d_in[0];
    const float* W_enc = (const float*)d_in[1];
    const float* b_enc = (const float*)d_in[2];
    const float* W1    = (const float*)d_in[3];
    const float* b1    = (const float*)d_in[4];
    const float* W2    = (const float*)d_in[5];
    const float* b2    = (const float*)d_in[6];
    float* out = (float*)d_out;

    u32* ws = (u32*)d_ws;
    const int PLANE = 128 * 1024;          // u32 per plane = 512 KB
    u32* PAa = ws;
    u32* PAe = ws + PLANE;
    u32* PBb = ws + 2 * PLANE;
    u32* PBe = ws + 3 * PLANE;
    u32* W2h = ws + 4 * PLANE;
    float* basep = (float*)(ws + 4 * PLANE + 128);

    prep_kernel<<<257, 256, 0, stream>>>(x, W_enc, b_enc, W1, b1, W2, b2,
                                         PAa, PAe, PBb, PBe, W2h, basep);
    pair_kernel<<<dim3(16, 16), 256, 0, stream>>>(PAa, PAe, PBb, PBe, W2h,
                                                  basep, out);
}